// Round 5
// baseline (179.802 us; speedup 1.0000x reference)
//
#include <hip/hip_runtime.h>
#include <math.h>

#define NUM_NODE 5000
#define BZ   64
#define SEQ  512
#define NBR  16
#define DIM  256
#define NCLS 20

#define ROWB8   DIM                  // fp8 row bytes (256)
#define ESCALE  256.0f               // table scale (values ~0.02 -> ~5, e4m3 sweet spot)
#define CW      8                    // waves (=positions) per gather block
#define NCHUNK  (SEQ / CW)           // 64 partial chunks per batch row
#define CVT_N4  (NUM_NODE * DIM / 4) // 320000 float4s
#define NCHUNK16 (SEQ / 16)          // fallback mapping

typedef float v2f __attribute__((ext_vector_type(2)));

__device__ __forceinline__ int bcast_i(int v, int lane) {
    return __builtin_amdgcn_readlane(v, lane);   // uniform (SGPR) result
}
__device__ __forceinline__ float bcast_f(float v, int lane) {
    return __int_as_float(__builtin_amdgcn_readlane(__float_as_int(v), lane));
}

__global__ __launch_bounds__(256) void zero_ws_kernel(float* __restrict__ ws, int n) {
    int i = blockIdx.x * blockDim.x + threadIdx.x;
    if (i < n) ws[i] = 0.0f;
}

// fp32 (NUM_NODE,DIM) -> scaled fp8 e4m3 table (5 MB read, 1.28 MB write).
__global__ __launch_bounds__(256) void cvt_emb_kernel(
    const float4* __restrict__ src, unsigned* __restrict__ dst, int n4) {
    int i = blockIdx.x * blockDim.x + threadIdx.x;
    if (i < n4) {
        float4 v = src[i];
        int r = 0;
        r = __builtin_amdgcn_cvt_pk_fp8_f32(v.x * ESCALE, v.y * ESCALE, r, false);
        r = __builtin_amdgcn_cvt_pk_fp8_f32(v.z * ESCALE, v.w * ESCALE, r, true);
        dst[i] = (unsigned)r;
    }
}

// Fused gather, fp8 rows, MINIMAL ADDRESS STREAM. Evidence (R2-R4): gather
// duration is invariant to row bytes (bf16->fp8 neutral), atomics, and
// edge-chase placement, but sensitive to occupancy — i.e. bound by the
// vmem address/instruction pipe + latency chains, not data width. So this
// version cuts vmem instructions per position 14 -> 9:
//   - uint4 (16B)/lane: 16 lanes cover a whole 256B fp8 row -> quarter-wave
//     per neighbor, 4 instructions cover all 16 neighbors (+1 self).
//   - NX and EW index loads fused into ONE per-lane-pointer load
//     (lanes 0-15 NX, lanes 16-31 EW).
// Neighbor ids / weights reach their quarter-wave via __shfl (ds_bpermute
// supports the q-divergent source lane; readlane can't). Issue order:
// fused idx -> edge_w chase -> 4 nbr rows + self (vmcnt retires in-order,
// so the HBM-cold edge line arrives under the L2 row loads). Epilogue:
// lanes of quarter 0 write 16 dims each to LDS, block folds 8 positions,
// un-scales, streams 1 KB to part[b][chunk][:]. No atomics, no init.
__global__ __launch_bounds__(512, 8) void gnn_gather_kernel(
    const int*   __restrict__ X,        // (BZ, SEQ)
    const int*   __restrict__ NX,       // (BZ, SEQ, NBR)
    const int*   __restrict__ EW,       // (BZ, SEQ, NBR)
    const char*  __restrict__ emb8,     // (NUM_NODE, ROWB8) scaled fp8 table
    const float* __restrict__ edge_w,   // (EDGE_ROWS, 1)
    const float* __restrict__ node_w,   // (NUM_NODE, 1)
    float*       __restrict__ part)     // (BZ, NCHUNK, DIM) partials
{
    __shared__ float lds[CW][DIM];

    const int b     = blockIdx.x / NCHUNK;
    const int chunk = blockIdx.x % NCHUNK;
    const int wave  = threadIdx.x >> 6;
    const int lane  = threadIdx.x & 63;
    const int q     = lane >> 4;         // quarter-wave id (0..3)
    const int r     = lane & 15;
    const int voff  = r * 16;            // byte offset within an fp8 row

    const int s  = chunk * CW + wave;
    const int bs = b * SEQ + s;

    // ONE fused index load: lanes 0-15 = NX row, lanes 16-31 = EW row.
    int iv = 0;
    if (lane < 32) {
        const int* p = (lane < 16) ? &NX[bs * NBR + r] : &EW[bs * NBR + r];
        iv = __builtin_nontemporal_load(p);
    }
    // EW -> edge_w chase (lanes 16-31): the one HBM-cold random gather,
    // issued before the row loads so it retires under them.
    float ewv = 0.f;
    if (lane >= 16 && lane < 32) ewv = edge_w[iv];

    const int   x  = X[bs];        // wave-uniform address -> broadcast line
    const float nn = node_w[x];

    // neighbor ids for this lane's 4 row loads: neighbor (4g+q)
    int na[4];
    #pragma unroll
    for (int g = 0; g < 4; ++g) na[g] = __shfl(iv, 4 * g + q);

    // ---- 5 row-load instructions total ----
    uint4 e[4];
    #pragma unroll
    for (int g = 0; g < 4; ++g)
        e[g] = *(const uint4*)(emb8 + (size_t)na[g] * ROWB8 + voff);
    const uint4 es = *(const uint4*)(emb8 + (size_t)x * ROWB8 + voff); // self

    // ---- consume: this lane owns dims [16r, 16r+16) ----
    float m[16];
    #pragma unroll
    for (int k = 0; k < 16; ++k) m[k] = -INFINITY;

    #pragma unroll
    for (int g = 0; g < 4; ++g) {
        const float w = __shfl(ewv, 16 + 4 * g + q);   // weight of nbr (4g+q)
        const unsigned wd[4] = {e[g].x, e[g].y, e[g].z, e[g].w};
        #pragma unroll
        for (int d = 0; d < 4; ++d) {
            const v2f lo = __builtin_amdgcn_cvt_pk_f32_fp8((int)wd[d], false);
            const v2f hi = __builtin_amdgcn_cvt_pk_f32_fp8((int)wd[d], true);
            m[4 * d + 0] = fmaxf(m[4 * d + 0], lo.x * w);
            m[4 * d + 1] = fmaxf(m[4 * d + 1], lo.y * w);
            m[4 * d + 2] = fmaxf(m[4 * d + 2], hi.x * w);
            m[4 * d + 3] = fmaxf(m[4 * d + 3], hi.y * w);
        }
    }
    // combine the four quarter-wave neighbor subsets
    #pragma unroll
    for (int k = 0; k < 16; ++k) m[k] = fmaxf(m[k], __shfl_xor(m[k], 16));
    #pragma unroll
    for (int k = 0; k < 16; ++k) m[k] = fmaxf(m[k], __shfl_xor(m[k], 32));

    // weighted combine with self row (in place, keeps VGPRs <= 64)
    const float om = 1.0f - nn;
    {
        const unsigned wd[4] = {es.x, es.y, es.z, es.w};
        #pragma unroll
        for (int d = 0; d < 4; ++d) {
            const v2f lo = __builtin_amdgcn_cvt_pk_f32_fp8((int)wd[d], false);
            const v2f hi = __builtin_amdgcn_cvt_pk_f32_fp8((int)wd[d], true);
            m[4 * d + 0] = om * m[4 * d + 0] + nn * lo.x;
            m[4 * d + 1] = om * m[4 * d + 1] + nn * lo.y;
            m[4 * d + 2] = om * m[4 * d + 2] + nn * hi.x;
            m[4 * d + 3] = om * m[4 * d + 3] + nn * hi.y;
        }
    }

    if (q == 0) {
        #pragma unroll
        for (int d = 0; d < 4; ++d)
            *(float4*)&lds[wave][16 * r + 4 * d] =
                make_float4(m[4 * d], m[4 * d + 1], m[4 * d + 2], m[4 * d + 3]);
    }
    __syncthreads();

    if (threadIdx.x < DIM) {
        float ssum = 0.f;
        #pragma unroll
        for (int w2 = 0; w2 < CW; ++w2) ssum += lds[w2][threadIdx.x];
        // un-scale the x256 table here (one multiply per output element)
        part[((size_t)b * NCHUNK + chunk) * DIM + threadIdx.x] = ssum * (1.0f / ESCALE);
    }
}

// Fallback (tiny ws): fp32 gathers, atomic accumulation into (BZ,DIM).
__global__ __launch_bounds__(256) void gnn_gather_f32_kernel(
    const int*   __restrict__ X,
    const int*   __restrict__ NX,
    const int*   __restrict__ EW,
    const float* __restrict__ node_emb,
    const float* __restrict__ edge_w,
    const float* __restrict__ node_w,
    float*       __restrict__ dst)      // (BZ, DIM) atomic
{
    __shared__ float lds[4][DIM];
    const int b     = blockIdx.x / NCHUNK16;
    const int chunk = blockIdx.x % NCHUNK16;
    const int wave  = threadIdx.x >> 6;
    const int lane  = threadIdx.x & 63;
    const int s0  = chunk * 16 + wave * 4;
    const int bs0 = b * SEQ + s0;

    const int   nx  = NX[bs0 * NBR + lane];
    const float ew  = edge_w[EW[bs0 * NBR + lane]];
    int xv = 0; float nwv = 0.f;
    if (lane < 4) { xv = X[bs0 + lane]; nwv = node_w[xv]; }

    float4 acc = make_float4(0.f, 0.f, 0.f, 0.f);
    for (int p = 0; p < 4; ++p) {
        float4 m = make_float4(-INFINITY, -INFINITY, -INFINITY, -INFINITY);
        for (int k = 0; k < NBR; ++k) {
            const int   n = bcast_i(nx, p * 16 + k);
            const float w = bcast_f(ew, p * 16 + k);
            const float4 e = *(const float4*)(node_emb + (size_t)n * DIM + 4 * lane);
            m.x = fmaxf(m.x, e.x * w); m.y = fmaxf(m.y, e.y * w);
            m.z = fmaxf(m.z, e.z * w); m.w = fmaxf(m.w, e.w * w);
        }
        const int   x  = bcast_i(xv, p);
        const float nn = bcast_f(nwv, p);
        const float om = 1.0f - nn;
        const float4 r = *(const float4*)(node_emb + (size_t)x * DIM + 4 * lane);
        acc.x += om * m.x + nn * r.x; acc.y += om * m.y + nn * r.y;
        acc.z += om * m.z + nn * r.z; acc.w += om * m.w + nn * r.w;
    }
    *(float4*)&lds[wave][4 * lane] = acc;
    __syncthreads();
    const int t = threadIdx.x;
    atomicAdd(&dst[b * DIM + t], lds[0][t] + lds[1][t] + lds[2][t] + lds[3][t]);
}

// One block (256 threads) per batch row: fold nchunk partials (streaming)
// then GEMV(256->20) + bias + relu + log_softmax.
__global__ __launch_bounds__(256) void gnn_head_kernel(
    const float* __restrict__ part,  // (BZ, nchunk, DIM)
    const int                 nchunk,
    const float* __restrict__ fc_W,  // (NCLS, DIM)
    const float* __restrict__ fc_b,  // (NCLS,)
    float*       __restrict__ out)   // (BZ, NCLS)
{
    __shared__ float4 lds4[4][64];
    __shared__ float vals[NCLS];
    __shared__ float lse;

    const int b = blockIdx.x;
    const int t = threadIdx.x;
    const int wave = t >> 6;
    const int lane = t & 63;

    // fold partials: wave w sums chunks w, w+4, w+8, ...
    float4 y = make_float4(0.f, 0.f, 0.f, 0.f);
    for (int c = wave; c < nchunk; c += 4) {
        const float4 v = *(const float4*)(part + ((size_t)b * nchunk + c) * DIM + 4 * lane);
        y.x += v.x; y.y += v.y; y.z += v.z; y.w += v.w;
    }
    lds4[wave][lane] = y;
    __syncthreads();
    const float4 a0 = lds4[0][lane], a1 = lds4[1][lane];
    const float4 a2 = lds4[2][lane], a3 = lds4[3][lane];
    const float4 y4 = make_float4(a0.x + a1.x + a2.x + a3.x,
                                  a0.y + a1.y + a2.y + a3.y,
                                  a0.z + a1.z + a2.z + a3.z,
                                  a0.w + a1.w + a2.w + a3.w);

    #pragma unroll
    for (int ci = 0; ci < 5; ++ci) {
        const int c = wave * 5 + ci;           // 4 waves x 5 classes = 20
        const float4 w4 = *(const float4*)(fc_W + c * DIM + 4 * lane);
        float d = y4.x * w4.x + y4.y * w4.y + y4.z * w4.z + y4.w * w4.w;
        #pragma unroll
        for (int off = 32; off; off >>= 1) d += __shfl_xor(d, off);
        if (lane == 0) vals[c] = fmaxf(d + fc_b[c], 0.0f);
    }
    __syncthreads();

    if (t == 0) {
        float mx = -INFINITY;
        for (int c = 0; c < NCLS; ++c) mx = fmaxf(mx, vals[c]);
        float s = 0.0f;
        for (int c = 0; c < NCLS; ++c) s += expf(vals[c] - mx);
        lse = mx + logf(s);
    }
    __syncthreads();

    if (t < NCLS) out[b * NCLS + t] = vals[t] - lse;
}

extern "C" void kernel_launch(void* const* d_in, const int* in_sizes, int n_in,
                              void* d_out, int out_size, void* d_ws, size_t ws_size,
                              hipStream_t stream) {
    const int*   X        = (const int*)  d_in[0];
    const int*   NX       = (const int*)  d_in[1];
    const int*   EW       = (const int*)  d_in[2];
    const float* node_emb = (const float*)d_in[3];
    const float* edge_w   = (const float*)d_in[4];
    const float* node_w   = (const float*)d_in[5];
    const float* fc_W     = (const float*)d_in[6];
    const float* fc_b     = (const float*)d_in[7];
    float* out = (float*)d_out;

    const size_t part_bytes = (size_t)BZ * NCHUNK * DIM * sizeof(float);  // 4 MB
    const size_t emb_bytes  = (size_t)NUM_NODE * DIM;                     // 1.28 MB fp8
    float* part = (float*)d_ws;
    char*  emb8 = (char*)d_ws + part_bytes;

    if (ws_size >= part_bytes + emb_bytes) {
        cvt_emb_kernel<<<(CVT_N4 + 255) / 256, 256, 0, stream>>>(
            (const float4*)node_emb, (unsigned*)emb8, CVT_N4);
        gnn_gather_kernel<<<BZ * NCHUNK, 512, 0, stream>>>(
            X, NX, EW, emb8, edge_w, node_w, part);
        gnn_head_kernel<<<BZ, 256, 0, stream>>>(part, NCHUNK, fc_W, fc_b, out);
    } else {
        zero_ws_kernel<<<(BZ * DIM + 255) / 256, 256, 0, stream>>>(part, BZ * DIM);
        gnn_gather_f32_kernel<<<BZ * NCHUNK16, 256, 0, stream>>>(
            X, NX, EW, node_emb, edge_w, node_w, part);
        gnn_head_kernel<<<BZ, 256, 0, stream>>>(part, 1, fc_W, fc_b, out);
    }
}